// Round 2
// baseline (107.447 us; speedup 1.0000x reference)
//
#include <hip/hip_runtime.h>

#define BATCH 512
#define DIN 512
#define NCLS 16
#define NNODES 100000
#define CBLK 256
#define NODE_BLOCKS ((NNODES + CBLK - 1) / CBLK)   // 391

// ---- workspace layout (bytes) ----
// best:       [0, 4096)      512 x u64 packed (ford(sim) << 32 | (~node_idx))
// probs:      [4096, 36864)  512 x 16 f32
// emb:        [36864, 40960) 512 x 2 f32
// sorted_ids: [40960, 43008) 512 x i32, sample ids sorted by pred class
// class_off:  [43008, 43136) 17 x i32 prefix offsets into sorted_ids
// done:       [43136, 43140) 1 x u32
#define WS_BEST   0
#define WS_PROBS  4096
#define WS_EMB    36864
#define WS_SORT   40960
#define WS_OFF    43008
#define WS_DONE   43136

__device__ __forceinline__ unsigned ford(float f) {
    unsigned bits = __float_as_uint(f);
    return (bits & 0x80000000u) ? ~bits : (bits | 0x80000000u);
}

// 65 blocks x 512 threads.
// Blocks 0..63: emb = train_data @ W + b, one sample per wave (8 waves/block).
// Block 64:     softmax+argmax per sample, class-sorted sample list, init best/done.
__global__ __launch_bounds__(512) void prep_kernel(
    const float* __restrict__ logits,
    const float* __restrict__ train_data,
    const float* __restrict__ W,
    const float* __restrict__ bvec,
    float* __restrict__ probs,
    float* __restrict__ emb,
    int* __restrict__ sorted_ids,
    int* __restrict__ class_off,
    unsigned long long* __restrict__ best,
    unsigned int* __restrict__ done) {
    if (blockIdx.x < 64) {
        const int wave = threadIdx.x >> 6;
        const int lane = threadIdx.x & 63;
        const int s = blockIdx.x * 8 + wave;
        const float* td = train_data + s * DIN;
        const float2* W2 = (const float2*)W;
        float a0 = 0.f, a1 = 0.f;
        for (int k = lane; k < DIN; k += 64) {
            float t = td[k];
            float2 w = W2[k];
            a0 += t * w.x;
            a1 += t * w.y;
        }
        for (int off = 32; off; off >>= 1) {
            a0 += __shfl_down(a0, off);
            a1 += __shfl_down(a1, off);
        }
        if (lane == 0) {
            emb[2 * s]     = a0 + bvec[0];
            emb[2 * s + 1] = a1 + bvec[1];
        }
    } else {
        __shared__ int scnt[NCLS];
        __shared__ int soff[NCLS + 1];
        const int s = threadIdx.x;
        if (s < NCLS) scnt[s] = 0;

        const float4* lg = (const float4*)(logits + s * NCLS);
        float4 x0 = lg[0], x1 = lg[1], x2 = lg[2], x3 = lg[3];
        float v[NCLS] = {x0.x, x0.y, x0.z, x0.w, x1.x, x1.y, x1.z, x1.w,
                         x2.x, x2.y, x2.z, x2.w, x3.x, x3.y, x3.z, x3.w};
        float m = v[0];
        int pred = 0;
        #pragma unroll
        for (int j = 1; j < NCLS; ++j)
            if (v[j] > m) { m = v[j]; pred = j; }
        float sum = 0.f;
        #pragma unroll
        for (int j = 0; j < NCLS; ++j) { v[j] = expf(v[j] - m); sum += v[j]; }
        float inv = 1.0f / sum;
        float4* p4 = (float4*)(probs + s * NCLS);
        p4[0] = make_float4(v[0] * inv, v[1] * inv, v[2] * inv, v[3] * inv);
        p4[1] = make_float4(v[4] * inv, v[5] * inv, v[6] * inv, v[7] * inv);
        p4[2] = make_float4(v[8] * inv, v[9] * inv, v[10] * inv, v[11] * inv);
        p4[3] = make_float4(v[12] * inv, v[13] * inv, v[14] * inv, v[15] * inv);

        best[s] = 0ull;  // strictly below any finite packed sim

        __syncthreads();
        int pos = atomicAdd(&scnt[pred], 1);
        __syncthreads();
        if (s == 0) {
            int acc = 0;
            for (int c = 0; c < NCLS; ++c) { soff[c] = acc; acc += scnt[c]; }
            soff[NCLS] = acc;
            *done = 0u;
        }
        __syncthreads();
        sorted_ids[soff[pred] + pos] = s;
        if (s <= NCLS) class_off[s] = soff[s];
    }
}

// 391 blocks x 256 threads; one node per thread. Last finished block finalizes.
__global__ __launch_bounds__(256) void nodes_kernel(
    const float* __restrict__ all_nodes,
    const float* __restrict__ probs,
    const int* __restrict__ sorted_ids,
    const int* __restrict__ class_off,
    unsigned long long* __restrict__ best,
    unsigned int* __restrict__ done,
    const float* __restrict__ emb,
    const float* __restrict__ all_nodes_2d,
    float* __restrict__ out) {
    // sp4[j*512 + s]: SoA by float4 so random-s ds_read_b128 spreads quads (s&7)
    __shared__ float4 sp4[4 * BATCH];               // 32 KB
    __shared__ unsigned long long lbest[BATCH];     // 4 KB
    __shared__ int ssort[BATCH];                    // 2 KB
    __shared__ int soff[NCLS + 1];
    __shared__ int slast;
    __shared__ float part[4];

    const int t = threadIdx.x;

    const float4* p4 = (const float4*)probs;
    for (int i = t; i < 4 * BATCH; i += CBLK)
        sp4[(i & 3) * BATCH + (i >> 2)] = p4[i];
    for (int i = t; i < BATCH; i += CBLK) {
        lbest[i] = 0ull;
        ssort[i] = sorted_ids[i];
    }
    if (t <= NCLS) soff[t] = class_off[t];
    __syncthreads();

    const int n = blockIdx.x * CBLK + t;
    if (n < NNODES) {
        const float4* nv = (const float4*)(all_nodes + n * NCLS);
        float4 v0 = nv[0], v1 = nv[1], v2 = nv[2], v3 = nv[3];
        float vals[NCLS] = {v0.x, v0.y, v0.z, v0.w, v1.x, v1.y, v1.z, v1.w,
                            v2.x, v2.y, v2.z, v2.w, v3.x, v3.y, v3.z, v3.w};
        int cls = 0;
        float m = vals[0];
        float nrm2 = 0.f;
        #pragma unroll
        for (int j = 0; j < NCLS; ++j) {
            if (j > 0 && vals[j] > m) { m = vals[j]; cls = j; }
            nrm2 += vals[j] * vals[j];
        }
        float inv_norm = 1.0f / sqrtf(nrm2);
        unsigned low = 0xFFFFFFFFu - (unsigned)n;

        const int i0 = soff[cls], i1 = soff[cls + 1];
        for (int i = i0; i < i1; ++i) {
            int s = ssort[i];
            float4 a0 = sp4[s];
            float4 a1 = sp4[BATCH + s];
            float4 a2 = sp4[2 * BATCH + s];
            float4 a3 = sp4[3 * BATCH + s];
            float dot = a0.x * v0.x + a0.y * v0.y + a0.z * v0.z + a0.w * v0.w
                      + a1.x * v1.x + a1.y * v1.y + a1.z * v1.z + a1.w * v1.w
                      + a2.x * v2.x + a2.y * v2.y + a2.z * v2.z + a2.w * v2.w
                      + a3.x * v3.x + a3.y * v3.y + a3.z * v3.z + a3.w * v3.w;
            float sim = dot * inv_norm;
            unsigned long long packed =
                ((unsigned long long)ford(sim) << 32) | (unsigned long long)low;
            if (packed > lbest[s]) atomicMax(&lbest[s], packed);
        }
    }
    __syncthreads();
    for (int i = t; i < BATCH; i += CBLK) {
        unsigned long long b = lbest[i];
        if (b) atomicMax(&best[i], b);
    }
    __threadfence();
    __syncthreads();
    if (t == 0)
        slast = (atomicAdd(done, 1u) == (unsigned)(gridDim.x - 1)) ? 1 : 0;
    __syncthreads();
    if (slast) {
        float v = 0.f;
        for (int i = t; i < BATCH; i += CBLK) {
            unsigned long long p = atomicMax(&best[i], 0ull);  // coherent read
            int idx = (p == 0ull) ? 0
                                  : (int)(0xFFFFFFFFu - (unsigned)(p & 0xFFFFFFFFull));
            float2 tgt = ((const float2*)all_nodes_2d)[idx];
            float2 e = ((const float2*)emb)[i];
            float d0 = e.x - tgt.x;
            float d1 = e.y - tgt.y;
            v += 0.5f * (d0 * d0 + d1 * d1);
        }
        for (int off = 32; off; off >>= 1) v += __shfl_down(v, off);
        if ((t & 63) == 0) part[t >> 6] = v;
        __syncthreads();
        if (t == 0)
            out[0] = (part[0] + part[1] + part[2] + part[3]) / (float)BATCH;
    }
}

extern "C" void kernel_launch(void* const* d_in, const int* in_sizes, int n_in,
                              void* d_out, int out_size, void* d_ws, size_t ws_size,
                              hipStream_t stream) {
    const float* logits       = (const float*)d_in[0];
    const float* train_data   = (const float*)d_in[1];
    const float* all_nodes    = (const float*)d_in[2];
    const float* all_nodes_2d = (const float*)d_in[3];
    const float* W            = (const float*)d_in[4];
    const float* bvec         = (const float*)d_in[5];
    float* out = (float*)d_out;

    char* ws = (char*)d_ws;
    unsigned long long* best = (unsigned long long*)(ws + WS_BEST);
    float* probs             = (float*)(ws + WS_PROBS);
    float* emb               = (float*)(ws + WS_EMB);
    int* sorted_ids          = (int*)(ws + WS_SORT);
    int* class_off           = (int*)(ws + WS_OFF);
    unsigned int* done       = (unsigned int*)(ws + WS_DONE);

    prep_kernel<<<65, 512, 0, stream>>>(logits, train_data, W, bvec,
                                        probs, emb, sorted_ids, class_off,
                                        best, done);

    nodes_kernel<<<NODE_BLOCKS, CBLK, 0, stream>>>(all_nodes, probs,
                                                   sorted_ids, class_off,
                                                   best, done,
                                                   emb, all_nodes_2d, out);
}